// Round 3
// baseline (222.606 us; speedup 1.0000x reference)
//
#include <hip/hip_runtime.h>
#include <math.h>

#define NVOX 50000
#define PPTS 32
#define HDIM 64
#define ODIM 128
#define EPSBN 1e-5f

// f16 row stride for activation tiles: 72 f16 = 144 B.
// Per 8-lane b128 phase: start bank = (4*m16)%32 -> 8 distinct 4-bank groups,
// conflict-free. b64 writes: 2-way (free, m136).
#define RS 72

typedef _Float16 f16x8 __attribute__((ext_vector_type(8)));
typedef _Float16 f16x4 __attribute__((ext_vector_type(4)));
typedef float f32x4 __attribute__((ext_vector_type(4)));

// d_ws layout (f16 elements unless noted):
//   [0, 512)       W1c: 64 rows x 8 f16  {w0..w3, c1, 0,0,0}   (BN-folded layer1)
//   [512, 4608)    W2T: [ch_out][ch_in] 64x64, BN-folded
//   [4608, 12800)  W3T: [o][ch_in] 128x64
//   byte 25600:    f32 c2[64], f32 b3[128]
#define WS_W1C 0
#define WS_W2T 512
#define WS_W3T 4608
#define WS_F32_BYTE 25600
#define FOLD_THREADS 12992

__global__ void vfe_fold(
    const float* __restrict__ W1, const float* __restrict__ b1,
    const float* __restrict__ g1, const float* __restrict__ be1,
    const float* __restrict__ m1, const float* __restrict__ v1,
    const float* __restrict__ W2, const float* __restrict__ b2,
    const float* __restrict__ g2, const float* __restrict__ be2,
    const float* __restrict__ m2, const float* __restrict__ v2,
    const float* __restrict__ W3, const float* __restrict__ b3,
    _Float16* __restrict__ wsh, float* __restrict__ wsf)
{
    int t = blockIdx.x * 256 + threadIdx.x;
    if (t < 512) {                               // W1c
        int row = t >> 3, i = t & 7;
        float s1 = g1[row] * rsqrtf(v1[row] + EPSBN);
        float val;
        if (i < 4)      val = W1[i * 64 + row] * s1;
        else if (i == 4) val = (b1[row] - m1[row]) * s1 + be1[row];
        else             val = 0.f;
        wsh[WS_W1C + t] = (_Float16)val;
    } else if (t < 4608) {                       // W2T folded: [ch'][ch]
        int e = t - 512;
        int chp = e >> 6, ch = e & 63;
        float s2 = g2[chp] * rsqrtf(v2[chp] + EPSBN);
        wsh[t] = (_Float16)(W2[ch * 64 + chp] * s2);
    } else if (t < 12800) {                      // W3T: [o][ch]
        int e = t - 4608;
        int o = e >> 6, ch = e & 63;
        wsh[t] = (_Float16)W3[ch * 128 + o];
    } else if (t < 12864) {                      // c2
        int i = t - 12800;
        float s2 = g2[i] * rsqrtf(v2[i] + EPSBN);
        wsf[i] = (b2[i] - m2[i]) * s2 + be2[i];
    } else if (t < FOLD_THREADS) {               // b3
        int i = t - 12864;
        wsf[64 + i] = b3[i];
    }
}

__global__ __launch_bounds__(256, 2) void vfe_mfma(
    const float* __restrict__ vf, const int* __restrict__ vnp,
    const _Float16* __restrict__ wsh, const float* __restrict__ wsf,
    float* __restrict__ out)
{
    // only LDS: per-wave activation round-trip tiles (C-layout -> A-layout)
    __shared__ __align__(16) _Float16 sH[4][2][16 * RS];

    const int tid  = threadIdx.x;
    const int wave = tid >> 6;
    const int lane = tid & 63;
    const int q    = lane >> 4;
    const int m16  = lane & 15;

    const int wavebase = blockIdx.x * 256 + wave * 64;  // 64 points = 2 voxels
    const int voxA = wavebase >> 5;

    // ---- register preloads straight from global (L2-resident) ----
    f16x8 a1[4];
#pragma unroll
    for (int mt = 0; mt < 4; ++mt) {
        f16x8 t = *(const f16x8*)&wsh[WS_W1C + (m16 + 16 * mt) * 8];
        a1[mt] = (q == 0) ? t : (f16x8)0;      // k = q*8+j; only k<8 carries data
    }
    f16x8 a2[4][2];
#pragma unroll
    for (int mt = 0; mt < 4; ++mt)
#pragma unroll
        for (int kk = 0; kk < 2; ++kk)
            a2[mt][kk] = *(const f16x8*)&wsh[WS_W2T + (m16 + 16 * mt) * 64 + kk * 32 + q * 8];
    f16x8 b3f[8][2];
#pragma unroll
    for (int nt = 0; nt < 8; ++nt)
#pragma unroll
        for (int kk = 0; kk < 2; ++kk)
            b3f[nt][kk] = *(const f16x8*)&wsh[WS_W3T + (m16 + 16 * nt) * 64 + kk * 32 + q * 8];
    f32x4 c2v[4];
#pragma unroll
    for (int mt = 0; mt < 4; ++mt)
        c2v[mt] = *(const f32x4*)(wsf + mt * 16 + q * 4);
    float b3r[8];
#pragma unroll
    for (int nt = 0; nt < 8; ++nt) b3r[nt] = wsf[64 + nt * 16 + m16];

    _Float16* h1t = &sH[wave][0][0];
    _Float16* h2t = &sH[wave][1][0];

#pragma unroll
    for (int v = 0; v < 2; ++v) {                // voxel voxA+v
        const int n = vnp[voxA + v];
        float vmax[8];
#pragma unroll
        for (int nt = 0; nt < 8; ++nt) vmax[nt] = -INFINITY;

#pragma unroll
        for (int p2 = 0; p2 < 2; ++p2) {         // 16-point half of the voxel
            const int pt = wavebase + v * 32 + p2 * 16 + m16;
            float4 xv = *(const float4*)(vf + (size_t)pt * 4);
            f16x8 bfrag = (f16x8)0;
            if (q == 0) {
                bfrag[0] = (_Float16)xv.x; bfrag[1] = (_Float16)xv.y;
                bfrag[2] = (_Float16)xv.z; bfrag[3] = (_Float16)xv.w;
                bfrag[4] = (_Float16)1.0f;       // homogeneous slot carries c1
            }

            // ---- layer 1 (transposed): D1[ch'][pt16] ----
#pragma unroll
            for (int mt = 0; mt < 4; ++mt) {
                f32x4 acc = {0.f, 0.f, 0.f, 0.f};
                acc = __builtin_amdgcn_mfma_f32_16x16x32_f16(a1[mt], bfrag, acc, 0, 0, 0);
                f16x4 h;
                h[0] = (_Float16)fmaxf(acc[0], 0.f);
                h[1] = (_Float16)fmaxf(acc[1], 0.f);
                h[2] = (_Float16)fmaxf(acc[2], 0.f);
                h[3] = (_Float16)fmaxf(acc[3], 0.f);
                *(f16x4*)&h1t[m16 * RS + mt * 16 + q * 4] = h;
            }
            f16x8 b2f[2];
#pragma unroll
            for (int kk = 0; kk < 2; ++kk)
                b2f[kk] = *(const f16x8*)&h1t[m16 * RS + kk * 32 + q * 8];

            // ---- layer 2 (transposed): acc pre-loaded with folded bias c2 ----
#pragma unroll
            for (int mt = 0; mt < 4; ++mt) {
                f32x4 acc = c2v[mt];
                acc = __builtin_amdgcn_mfma_f32_16x16x32_f16(a2[mt][0], b2f[0], acc, 0, 0, 0);
                acc = __builtin_amdgcn_mfma_f32_16x16x32_f16(a2[mt][1], b2f[1], acc, 0, 0, 0);
                f16x4 h;
                h[0] = (_Float16)fmaxf(acc[0], 0.f);
                h[1] = (_Float16)fmaxf(acc[1], 0.f);
                h[2] = (_Float16)fmaxf(acc[2], 0.f);
                h[3] = (_Float16)fmaxf(acc[3], 0.f);
                *(f16x4*)&h2t[m16 * RS + mt * 16 + q * 4] = h;
            }
            f16x8 a3[2];
#pragma unroll
            for (int kk = 0; kk < 2; ++kk)
                a3[kk] = *(const f16x8*)&h2t[m16 * RS + kk * 32 + q * 8];

            // ---- layer 3 (normal): acc pre-loaded with validity mask ----
            const int slotbase = p2 * 16 + q * 4;
            f32x4 macc;
#pragma unroll
            for (int r = 0; r < 4; ++r)
                macc[r] = (slotbase + r < n) ? 0.f : -INFINITY;

#pragma unroll
            for (int nt = 0; nt < 8; ++nt) {
                f32x4 acc = macc;
                acc = __builtin_amdgcn_mfma_f32_16x16x32_f16(a3[0], b3f[nt][0], acc, 0, 0, 0);
                acc = __builtin_amdgcn_mfma_f32_16x16x32_f16(a3[1], b3f[nt][1], acc, 0, 0, 0);
                float m0 = fmaxf(fmaxf(acc[0], acc[1]), fmaxf(acc[2], acc[3]));
                vmax[nt] = fmaxf(vmax[nt], m0);
            }
        }

        // ---- epilogue: reduce across quads, add bias, store ----
#pragma unroll
        for (int nt = 0; nt < 8; ++nt) {
            float t = vmax[nt];
            t = fmaxf(t, __shfl_xor(t, 16));
            t = fmaxf(t, __shfl_xor(t, 32));
            if (q == v)
                out[(size_t)(voxA + v) * ODIM + nt * 16 + m16] = t + b3r[nt];
        }
    }
}

extern "C" void kernel_launch(void* const* d_in, const int* in_sizes, int n_in,
                              void* d_out, int out_size, void* d_ws, size_t ws_size,
                              hipStream_t stream) {
    const float* vf  = (const float*)d_in[0];
    const int*   vnp = (const int*)d_in[1];
    const float* W1  = (const float*)d_in[2];
    const float* b1  = (const float*)d_in[3];
    const float* g1  = (const float*)d_in[4];
    const float* be1 = (const float*)d_in[5];
    const float* m1  = (const float*)d_in[6];
    const float* v1  = (const float*)d_in[7];
    const float* W2  = (const float*)d_in[8];
    const float* b2  = (const float*)d_in[9];
    const float* g2  = (const float*)d_in[10];
    const float* be2 = (const float*)d_in[11];
    const float* m2  = (const float*)d_in[12];
    const float* v2  = (const float*)d_in[13];
    const float* W3  = (const float*)d_in[14];
    const float* b3  = (const float*)d_in[15];
    float* out = (float*)d_out;

    _Float16* wsh = (_Float16*)d_ws;
    float*    wsf = (float*)((char*)d_ws + WS_F32_BYTE);

    vfe_fold<<<(FOLD_THREADS + 255) / 256, 256, 0, stream>>>(
        W1, b1, g1, be1, m1, v1, W2, b2, g2, be2, m2, v2, W3, b3, wsh, wsf);

    const int blocks = (NVOX * PPTS) / 256;   // 6250
    vfe_mfma<<<blocks, 256, 0, stream>>>(vf, vnp, wsh, wsf, out);
}